// Round 8
// baseline (443.658 us; speedup 1.0000x reference)
//
#include <hip/hip_runtime.h>

// Problem constants (fixed by setup_inputs): B=2, N=96, L=128
#define NANG 96
#define LDIM 128
#define NPIX (LDIM * LDIM)                 // 16384
#define IMG_ELEMS (2 * NANG * LDIM * LDIM) // 3,145,728
#define TPX 16                             // 4x4 pixel tile per block
#define NGRP 48                            // 2 angles per group
#define CHUNKB 4096                        // staged chunk: 256 c x 8 rows x 2B
#define CHUNK_STRIDE 4128                  // +32B pad
#define GRPB (4 * CHUNK_STRIDE)            // 16512 B per group buffer

typedef short short8 __attribute__((ext_vector_type(8)));

__device__ __forceinline__ ushort f2bf(float x) {   // f32 -> bf16 RNE
    union { float f; uint u; } v; v.f = x;
    const uint r = v.u + 0x7FFFu + ((v.u >> 16) & 1u);
    return (ushort)(r >> 16);
}
__device__ __forceinline__ float bf2f(ushort h) {
    union { uint u; float f; } v; v.u = ((uint)h) << 16;
    return v.f;
}

// ---- Pre-pass: f32 [b][n][row][z] -> bf16 [n][rowgrp=16][c=256][8 rows] --
// IDENTICAL to R6.
__global__ __launch_bounds__(256)
void convert_cm(const float* __restrict__ in, ushort* __restrict__ out) {
    const int blk = blockIdx.x;          // n*16 + rg
    const int n = blk >> 4;
    const int rg = blk & 15;
    const int t = threadIdx.x;           // = c = b*128 + z
    const int b = t >> 7;
    const int z = t & 127;
    const float* src = in + (((size_t)b * NANG + n) * LDIM + rg * 8) * LDIM + z;
    short8 w;
    #pragma unroll
    for (int j = 0; j < 8; ++j)
        w[j] = (short)f2bf(src[j * LDIM]);
    *(short8*)((char*)out + ((size_t)blk * 256 + t) * 16) = w;
}

// ---- BISECTION PROBE: R6 data path, VALU compute instead of MFMA --------
__global__ __launch_bounds__(256)
void backproj_probe(const ushort* __restrict__ imgcm,  // [n][16][256][8] bf16
                    const float* __restrict__ angles,  // [N]
                    float* __restrict__ out)           // [B, L, L, L] f32
{
    __shared__ uint2 geo[NANG][TPX];        // 12288 B: (wA|wB bf16s, offA|offB)
    __shared__ float4 smeta[NANG];          // 1536 B
    __shared__ float snorm[TPX];            // 64 B
    __shared__ __align__(16) char stage[2 * GRPB];  // 33024 B

    const int tid = threadIdx.x;
    const int r0 = (blockIdx.x >> 5) * 4;
    const int q0 = (blockIdx.x & 31) * 4;

    // ---- Phase 0: per-angle meta (IDENTICAL to R6) ----
    if (tid < NANG) {
        float s, c;
        sincosf((270.0f - angles[tid]) * 0.017453292519943295f, &s, &c);
        const float xrl = (float)q0 - 63.5f, xrh = xrl + 3.0f;
        const float yrl = (float)r0 - 63.5f, yrh = yrl + 3.0f;
        const float mn = fminf(c * xrl, c * xrh) + fminf(s * yrl, s * yrh) + 63.5f;
        int lo = min(max((int)floorf(mn), 0), LDIM - 1);
        const int g0 = min(lo >> 3, 14);
        smeta[tid] = make_float4(s, c, __int_as_float(g0),
                                 __int_as_float((tid * 16 + g0) * CHUNKB));
    }
    if (tid < TPX) snorm[tid] = 0.0f;
    __syncthreads();

    // ---- Phase 1: geometry (IDENTICAL to R6) ----
    for (int e = tid; e < NANG * TPX; e += 256) {
        const int n  = e >> 4;
        const int px = e & 15;
        const float4 m = smeta[n];
        const float s = m.x, c = m.y;
        const int g0 = __float_as_int(m.z);

        const float xr = (float)(q0 + (px & 3)) - 63.5f;
        const float yr = (float)(r0 + (px >> 2)) - 63.5f;
        const float sx =  c * xr + s * yr + 63.5f;
        const float sy = -s * xr + c * yr + 63.5f;

        const float x0f = floorf(sx), y0f = floorf(sy);
        const float wx = sx - x0f, wy = sy - y0f;
        const int x0 = (int)x0f, y0 = (int)y0f;

        const float vy0 = (y0 >= 0 && y0 < LDIM)         ? 1.0f : 0.0f;
        const float vy1 = (y0 + 1 >= 0 && y0 + 1 < LDIM) ? 1.0f : 0.0f;
        const float vx0 = (x0 >= 0 && x0 < LDIM)         ? 1.0f : 0.0f;
        const float vx1 = (x0 + 1 >= 0 && x0 + 1 < LDIM) ? 1.0f : 0.0f;
        const float yc = vy0 * (1.0f - wy) + vy1 * wy;

        float wA = (1.0f - wx) * yc * vx0;
        float wB = wx * yc * vx1;
        int offA = min(max(min(max(x0, 0), LDIM - 1) - g0 * 8, 0), 15);
        int offB = min(max(min(max(x0 + 1, 0), LDIM - 1) - g0 * 8, 0), 15);
        if (offA == offB) { wA += wB; wB = 0.0f; }

        const ushort ha = f2bf(wA);
        const ushort hb = f2bf(wB);
        geo[n][px] = make_uint2((uint)ha | ((uint)hb << 16),
                                (uint)offA | ((uint)offB << 8));
        atomicAdd(&snorm[px], bf2f(ha) + bf2f(hb));
    }

    const int wv   = tid >> 6;
    const int lane = tid & 63;
    const int lg   = lane >> 4;
    const int l15  = lane & 15;

    // stage one group (IDENTICAL to R6)
    auto issue_stage = [&](int g, int bufsel) {
        char* lbase = &stage[0] + bufsel * GRPB + wv * 1024;
        #pragma unroll
        for (int ci = 0; ci < 4; ++ci) {
            const int a = g * 2 + (ci >> 1);
            const int gbyte = __float_as_int(smeta[a].w) + (ci & 1) * CHUNKB;
            const char* gp = (const char*)imgcm + gbyte + wv * 1024 + l15 * 16 + lg * 256;
            __builtin_amdgcn_global_load_lds(
                (const __attribute__((address_space(1))) void*)gp,
                (__attribute__((address_space(3))) void*)(lbase + ci * CHUNK_STRIDE),
                16, 0, 0);
        }
    };

    // ---- VALU compute: thread owns column c = tid ----
    float accp[TPX];
    #pragma unroll
    for (int px = 0; px < TPX; ++px) accp[px] = 0.0f;

    auto compute = [&](int g, int bufsel) {
        const char* sbase = &stage[0] + bufsel * GRPB + tid * 16;
        #pragma unroll
        for (int al = 0; al < 2; ++al) {
            const int a = g * 2 + al;
            const char* cb = sbase + al * 2 * CHUNK_STRIDE;
            #pragma unroll
            for (int px = 0; px < TPX; ++px) {
                const uint2 gg = geo[a][px];
                const float wA = bf2f((ushort)(gg.x & 0xffff));
                const float wB = bf2f((ushort)(gg.x >> 16));
                const int offA = (int)(gg.y & 255);
                const int offB = (int)((gg.y >> 8) & 255);
                float vA, vB;
                if (offB == offA + 1 && (offA & 1) == 0 && (offA & 7) != 7) {
                    // aligned u32 pair read (wave-uniform branch)
                    const uint pr = *(const uint*)(cb + (offA >> 3) * CHUNK_STRIDE + (offA & 7) * 2);
                    vA = bf2f((ushort)(pr & 0xffff));
                    vB = bf2f((ushort)(pr >> 16));
                } else {
                    vA = bf2f(*(const ushort*)(cb + (offA >> 3) * CHUNK_STRIDE + (offA & 7) * 2));
                    vB = bf2f(*(const ushort*)(cb + (offB >> 3) * CHUNK_STRIDE + (offB & 7) * 2));
                }
                accp[px] = fmaf(wA, vA, accp[px]);
                accp[px] = fmaf(wB, vB, accp[px]);
            }
        }
    };

    issue_stage(0, 0);
    for (int g = 0; g < NGRP; ++g) {
        asm volatile("s_waitcnt vmcnt(0)" ::: "memory");
        __syncthreads();
        if (g + 1 < NGRP) issue_stage(g + 1, (g + 1) & 1);
        compute(g, g & 1);
    }

    // ---- Epilogue: thread c = tid -> (b, z); divide by snorm ----
    const int bb = tid >> 7;
    const int z  = tid & 127;
    #pragma unroll
    for (int px = 0; px < TPX; ++px) {
        const float inv = 1.0f / (snorm[px] + 1e-11f);
        const int r = r0 + (px >> 2);
        const int q = q0 + (px & 3);
        out[(((size_t)bb * LDIM + r) * LDIM + q) * LDIM + z] = accp[px] * inv;
    }
}

// ---- Fallback f32 kernel (proven in R0) if ws can't hold bf16 image ----
__global__ __launch_bounds__(256)
void backproj_f32(const float* __restrict__ image,
                  const float* __restrict__ angles,
                  float* __restrict__ out)
{
    __shared__ float4 geo[4 * NANG];
    const int tid = threadIdx.x;
    const int p0 = blockIdx.x * 4;

    for (int e = tid; e < 4 * NANG; e += 256) {
        const int sub = e / NANG;
        const int n   = e - sub * NANG;
        const int p   = p0 + sub;
        const int r   = p >> 7;
        const int q   = p & 127;
        float s, c;
        sincosf((270.0f - angles[n]) * 0.017453292519943295f, &s, &c);
        const float xr = (float)q - 63.5f;
        const float yr = (float)r - 63.5f;
        const float sx =  c * xr + s * yr + 63.5f;
        const float sy = -s * xr + c * yr + 63.5f;
        const float x0f = floorf(sx), y0f = floorf(sy);
        const float wx = sx - x0f, wy = sy - y0f;
        const int x0 = (int)x0f, y0 = (int)y0f;
        const float vy0 = (y0 >= 0 && y0 < LDIM) ? 1.0f : 0.0f;
        const float vy1 = (y0 + 1 >= 0 && y0 + 1 < LDIM) ? 1.0f : 0.0f;
        const float vx0 = (x0 >= 0 && x0 < LDIM) ? 1.0f : 0.0f;
        const float vx1 = (x0 + 1 >= 0 && x0 + 1 < LDIM) ? 1.0f : 0.0f;
        const float ycomb = vy0 * (1.0f - wy) + vy1 * wy;
        geo[e] = make_float4((1.0f - wx) * ycomb * vx0, wx * ycomb * vx1,
                             __int_as_float(min(max(x0, 0), LDIM - 1) * LDIM),
                             __int_as_float(min(max(x0 + 1, 0), LDIM - 1) * LDIM));
    }
    __syncthreads();

    const int sub  = tid >> 6;
    const int lane = tid & 63;
    const int b    = lane >> 5;
    const int z    = (lane & 31) * 4;
    const int p    = p0 + sub;
    const int r    = p >> 7;
    const int q    = p & 127;

    const float* imgb = image + (size_t)b * NANG * NPIX + z;
    const float4* __restrict__ gbase = &geo[sub * NANG];
    float4 acc = make_float4(0.f, 0.f, 0.f, 0.f);
    float nacc = 0.f;

    #pragma unroll 4
    for (int n = 0; n < NANG; ++n) {
        const float4 g = gbase[n];
        const float* rowbase = imgb + n * NPIX;
        const float4 v0 = *(const float4*)(rowbase + __float_as_int(g.z));
        const float4 v1 = *(const float4*)(rowbase + __float_as_int(g.w));
        acc.x = fmaf(g.x, v0.x, fmaf(g.y, v1.x, acc.x));
        acc.y = fmaf(g.x, v0.y, fmaf(g.y, v1.y, acc.y));
        acc.z = fmaf(g.x, v0.z, fmaf(g.y, v1.z, acc.z));
        acc.w = fmaf(g.x, v0.w, fmaf(g.y, v1.w, acc.w));
        nacc += g.x + g.y;
    }
    const float inv = 1.0f / (nacc + 1e-11f);
    *(float4*)(out + ((((size_t)b * LDIM + r) * LDIM + q) * LDIM + z)) =
        make_float4(acc.x * inv, acc.y * inv, acc.z * inv, acc.w * inv);
}

extern "C" void kernel_launch(void* const* d_in, const int* in_sizes, int n_in,
                              void* d_out, int out_size, void* d_ws, size_t ws_size,
                              hipStream_t stream) {
    const float* image  = (const float*)d_in[0];   // [2, 96, 128, 128] f32
    const float* angles = (const float*)d_in[1];   // [96] f32
    float* out = (float*)d_out;                    // [2, 128, 128, 128] f32

    const size_t need = (size_t)IMG_ELEMS * sizeof(ushort);  // 6.29 MB
    if (ws_size >= need) {
        ushort* imgcm = (ushort*)d_ws;
        convert_cm<<<NANG * 16, 256, 0, stream>>>(image, imgcm);
        backproj_probe<<<1024, 256, 0, stream>>>(imgcm, angles, out);
    } else {
        backproj_f32<<<NPIX / 4, 256, 0, stream>>>(image, angles, out);
    }
}

// Round 11
// 72.331 us; speedup vs baseline: 6.1337x; 6.1337x over previous
//
#include <hip/hip_runtime.h>
#include <hip/hip_fp16.h>

// Problem constants (fixed by setup_inputs): B=2, N=96, L=128
#define NANG 96
#define LDIM 128
#define NPIX (LDIM * LDIM)                 // 16384
#define IMG_ELEMS (2 * NANG * LDIM * LDIM) // 3,145,728
#define TPX 16                             // 4x4 pixel tile per block
#define WROWS 8                            // staged source rows per angle
#define ROWB 512                           // bytes per tap-row (2 b x 128 z x fp16)
#define NBUF 4                             // stage ring depth

union H8 { float4 f4; __half2 h2[4]; };

// ---- Pre-pass: f32 [b][n][row][z] -> f16 [n][row][b][z] (R4-proven) -----
__global__ __launch_bounds__(256)
void convert_transpose(const float* __restrict__ in, __half* __restrict__ out) {
    const int i = blockIdx.x * 256 + threadIdx.x;  // one thread per 8 elems
    const int rowid = i >> 4;                      // global input row (b,n,row)
    const int zo = i & 15;
    const int b = rowid / (NANG * LDIM);
    const int rem = rowid - b * (NANG * LDIM);     // n*128 + row

    const float4 a = *(const float4*)(in + (size_t)i * 8);
    const float4 c = *(const float4*)(in + (size_t)i * 8 + 4);
    H8 u;
    u.h2[0] = __float22half2_rn(make_float2(a.x, a.y));
    u.h2[1] = __float22half2_rn(make_float2(a.z, a.w));
    u.h2[2] = __float22half2_rn(make_float2(c.x, c.y));
    u.h2[3] = __float22half2_rn(make_float2(c.z, c.w));
    *(float4*)(out + ((size_t)(rem * 2 + b) * LDIM + zo * 8)) = u.f4;
}

// ---- Deep-pipelined LDS-staged fp16 backprojection ----------------------
// Block = 256 threads = 4 waves; tile = 4x4 = 16 pixels.
// 4-buffer stage ring, prefetch depth 3, counted vmcnt(2) (never 0 in loop),
// ONE barrier per angle. Compute identical to R4 (proven absmax 0.0078).
// Lane: pxw=lane>>5, b=(lane>>4)&1, zo=lane&15 (8 halfs per lane).
__global__ __launch_bounds__(256)
void backproj_lds(const __half* __restrict__ imgh,   // [n][row][b][z] f16
                  const float* __restrict__ angles,  // [N]
                  float* __restrict__ out)           // [B, L, L, L] f32
{
    __shared__ uint2 geo[TPX][NANG];        // 12288 B: (wA|wB halfs, offA*512|offB*512<<16)
    __shared__ float4 smeta[NANG];          // 1536 B: (s, c, slo, global byte)
    __shared__ float snorm[TPX];            // 64 B
    __shared__ __align__(16) char stage[NBUF][WROWS * ROWB]; // 16384 B

    const int tid = threadIdx.x;
    const int rt = blockIdx.x >> 5;    // 0..31
    const int qt = blockIdx.x & 31;    // 0..31
    const int r0 = rt * 4;
    const int q0 = qt * 4;

    // ---- Phase 0: per-angle meta (R4-proven) ----
    if (tid < NANG) {
        float s, c;
        sincosf((270.0f - angles[tid]) * 0.017453292519943295f, &s, &c);
        const float xrl = (float)q0 - 63.5f, xrh = xrl + 3.0f;
        const float yrl = (float)r0 - 63.5f, yrh = yrl + 3.0f;
        const float mn = fminf(c * xrl, c * xrh) + fminf(s * yrl, s * yrh) + 63.5f;
        const int lo = (int)floorf(mn);
        const int slo = min(max(lo, 0), LDIM - WROWS);
        smeta[tid] = make_float4(s, c, __int_as_float(slo),
                                 __int_as_float((tid * LDIM + slo) << 9));
    }
    if (tid < TPX) snorm[tid] = 0.0f;
    __syncthreads();

    // ---- Phase 1: geometry (R4 math, uint2-packed) ----
    for (int e = tid; e < TPX * NANG; e += 256) {
        const int px = e / NANG;
        const int n  = e - px * NANG;
        const float4 m = smeta[n];
        const float s = m.x, c = m.y;
        const int slo = __float_as_int(m.z);

        const float xr = (float)(q0 + (px & 3)) - 63.5f;
        const float yr = (float)(r0 + (px >> 2)) - 63.5f;
        const float sx =  c * xr + s * yr + 63.5f;
        const float sy = -s * xr + c * yr + 63.5f;

        const float x0f = floorf(sx), y0f = floorf(sy);
        const float wx = sx - x0f, wy = sy - y0f;
        const int x0 = (int)x0f, y0 = (int)y0f;

        const float vy0 = (y0 >= 0 && y0 < LDIM)         ? 1.0f : 0.0f;
        const float vy1 = (y0 + 1 >= 0 && y0 + 1 < LDIM) ? 1.0f : 0.0f;
        const float vx0 = (x0 >= 0 && x0 < LDIM)         ? 1.0f : 0.0f;
        const float vx1 = (x0 + 1 >= 0 && x0 + 1 < LDIM) ? 1.0f : 0.0f;
        const float ycomb = vy0 * (1.0f - wy) + vy1 * wy;

        const float wA = (1.0f - wx) * ycomb * vx0;
        const float wB = wx * ycomb * vx1;

        // window-relative row byte-offsets, clamped (binds only when weight ~0)
        const int offA = min(max(min(max(x0, 0), LDIM - 1) - slo, 0), WROWS - 1);
        const int offB = min(max(min(max(x0 + 1, 0), LDIM - 1) - slo, 0), WROWS - 1);

        const ushort ha = __half_as_ushort(__float2half(wA));
        const ushort hb = __half_as_ushort(__float2half(wB));
        geo[px][n] = make_uint2((uint)ha | ((uint)hb << 16),
                                (uint)(offA << 9) | ((uint)(offB << 9) << 16));
        atomicAdd(&snorm[px], wA + wB);   // norm is data-independent
    }

    const int wv   = tid >> 6;
    const int lane = tid & 63;
    const int pxw  = lane >> 5;
    const int b    = (lane >> 4) & 1;
    const int zo   = lane & 15;
    const int laneoff = b * 256 + zo * 16;   // byte offset within 512 B row

    // stage(a): 256 threads x 16 B = 4 KB window; 1 inst/wave
    auto issue_stage = [&](int a, int bufsel) {
        const int gb = __float_as_int(smeta[a].w);
        const char* gp = (const char*)imgh + gb + tid * 16;
        char* lp = &stage[bufsel][0] + (tid & 0xC0) * 16;  // wave-uniform base
        __builtin_amdgcn_global_load_lds(
            (const __attribute__((address_space(1))) void*)gp,
            (__attribute__((address_space(3))) void*)lp, 16, 0, 0);
    };

    __half2 acc[2][4] = {};

    auto compute = [&](int a, int bufsel) {
        const char* sb = &stage[bufsel][0];
        #pragma unroll
        for (int pass = 0; pass < 2; ++pass) {
            const int px = pass * 8 + wv * 2 + pxw;
            const uint2 g2 = geo[px][a];
            const __half2 wa2 = __half2half2(__ushort_as_half((ushort)(g2.x & 0xffff)));
            const __half2 wb2 = __half2half2(__ushort_as_half((ushort)(g2.x >> 16)));
            H8 u0, u1;
            u0.f4 = *(const float4*)(sb + ((g2.y & 0xffff) + laneoff));
            u1.f4 = *(const float4*)(sb + ((g2.y >> 16) + laneoff));
            #pragma unroll
            for (int k = 0; k < 4; ++k) {
                acc[pass][k] = __hfma2(wa2, u0.h2[k], acc[pass][k]);
                acc[pass][k] = __hfma2(wb2, u1.h2[k], acc[pass][k]);
            }
        }
    };

    // ---- Main loop: depth-3 prefetch, counted vmcnt, 1 barrier/angle ----
    issue_stage(0, 0);
    issue_stage(1, 1);
    issue_stage(2, 2);
    for (int a = 0; a < NANG - 3; ++a) {          // a = 0..92
        asm volatile("s_waitcnt vmcnt(2)" ::: "memory");  // stage(a) landed (this wave)
        __syncthreads();                          // all waves' stage(a) landed;
                                                  // all waves done with compute(a-1)
        issue_stage(a + 3, (a + 3) & (NBUF - 1)); // overwrites buf read at a-1: safe
        compute(a, a & (NBUF - 1));
    }
    asm volatile("s_waitcnt vmcnt(2)" ::: "memory");
    __syncthreads();
    compute(NANG - 3, (NANG - 3) & (NBUF - 1));   // 93
    asm volatile("s_waitcnt vmcnt(1)" ::: "memory");
    __syncthreads();
    compute(NANG - 2, (NANG - 2) & (NBUF - 1));   // 94
    asm volatile("s_waitcnt vmcnt(0)" ::: "memory");
    __syncthreads();
    compute(NANG - 1, (NANG - 1) & (NBUF - 1));   // 95

    // ---- Epilogue: fp16 acc -> f32, divide by precomputed norm ----
    #pragma unroll
    for (int pass = 0; pass < 2; ++pass) {
        const int px = pass * 8 + wv * 2 + pxw;
        const int r = r0 + (px >> 2);
        const int q = q0 + (px & 3);
        const float inv = 1.0f / (snorm[px] + 1e-11f);
        const float2 f0 = __half22float2(acc[pass][0]);
        const float2 f1 = __half22float2(acc[pass][1]);
        const float2 f2 = __half22float2(acc[pass][2]);
        const float2 f3 = __half22float2(acc[pass][3]);
        float* op = out + ((((size_t)b * LDIM + r) * LDIM + q) * LDIM + zo * 8);
        *(float4*)op     = make_float4(f0.x * inv, f0.y * inv, f1.x * inv, f1.y * inv);
        *(float4*)(op+4) = make_float4(f2.x * inv, f2.y * inv, f3.x * inv, f3.y * inv);
    }
}

// ---- Fallback f32 kernel (proven in R0) if ws can't hold fp16 image ----
__global__ __launch_bounds__(256)
void backproj_f32(const float* __restrict__ image,
                  const float* __restrict__ angles,
                  float* __restrict__ out)
{
    __shared__ float4 geo[4 * NANG];
    const int tid = threadIdx.x;
    const int p0 = blockIdx.x * 4;

    for (int e = tid; e < 4 * NANG; e += 256) {
        const int sub = e / NANG;
        const int n   = e - sub * NANG;
        const int p   = p0 + sub;
        const int r   = p >> 7;
        const int q   = p & 127;
        float s, c;
        sincosf((270.0f - angles[n]) * 0.017453292519943295f, &s, &c);
        const float xr = (float)q - 63.5f;
        const float yr = (float)r - 63.5f;
        const float sx =  c * xr + s * yr + 63.5f;
        const float sy = -s * xr + c * yr + 63.5f;
        const float x0f = floorf(sx), y0f = floorf(sy);
        const float wx = sx - x0f, wy = sy - y0f;
        const int x0 = (int)x0f, y0 = (int)y0f;
        const float vy0 = (y0 >= 0 && y0 < LDIM) ? 1.0f : 0.0f;
        const float vy1 = (y0 + 1 >= 0 && y0 + 1 < LDIM) ? 1.0f : 0.0f;
        const float vx0 = (x0 >= 0 && x0 < LDIM) ? 1.0f : 0.0f;
        const float vx1 = (x0 + 1 >= 0 && x0 + 1 < LDIM) ? 1.0f : 0.0f;
        const float ycomb = vy0 * (1.0f - wy) + vy1 * wy;
        geo[e] = make_float4((1.0f - wx) * ycomb * vx0, wx * ycomb * vx1,
                             __int_as_float(min(max(x0, 0), LDIM - 1) * LDIM),
                             __int_as_float(min(max(x0 + 1, 0), LDIM - 1) * LDIM));
    }
    __syncthreads();

    const int sub  = tid >> 6;
    const int lane = tid & 63;
    const int b    = lane >> 5;
    const int z    = (lane & 31) * 4;
    const int p    = p0 + sub;
    const int r    = p >> 7;
    const int q    = p & 127;

    const float* imgb = image + (size_t)b * NANG * NPIX + z;
    const float4* __restrict__ gbase = &geo[sub * NANG];
    float4 acc = make_float4(0.f, 0.f, 0.f, 0.f);
    float nacc = 0.f;

    #pragma unroll 4
    for (int n = 0; n < NANG; ++n) {
        const float4 g = gbase[n];
        const float* rowbase = imgb + n * NPIX;
        const float4 v0 = *(const float4*)(rowbase + __float_as_int(g.z));
        const float4 v1 = *(const float4*)(rowbase + __float_as_int(g.w));
        acc.x = fmaf(g.x, v0.x, fmaf(g.y, v1.x, acc.x));
        acc.y = fmaf(g.x, v0.y, fmaf(g.y, v1.y, acc.y));
        acc.z = fmaf(g.x, v0.z, fmaf(g.y, v1.z, acc.z));
        acc.w = fmaf(g.x, v0.w, fmaf(g.y, v1.w, acc.w));
        nacc += g.x + g.y;
    }
    const float inv = 1.0f / (nacc + 1e-11f);
    *(float4*)(out + ((((size_t)b * LDIM + r) * LDIM + q) * LDIM + z)) =
        make_float4(acc.x * inv, acc.y * inv, acc.z * inv, acc.w * inv);
}

extern "C" void kernel_launch(void* const* d_in, const int* in_sizes, int n_in,
                              void* d_out, int out_size, void* d_ws, size_t ws_size,
                              hipStream_t stream) {
    const float* image  = (const float*)d_in[0];   // [2, 96, 128, 128] f32
    const float* angles = (const float*)d_in[1];   // [96] f32
    float* out = (float*)d_out;                    // [2, 128, 128, 128] f32

    const size_t need = (size_t)IMG_ELEMS * sizeof(__half);  // 6.29 MB
    if (ws_size >= need) {
        __half* imgh = (__half*)d_ws;
        convert_transpose<<<IMG_ELEMS / 8 / 256, 256, 0, stream>>>(image, imgh);
        backproj_lds<<<1024, 256, 0, stream>>>(imgh, angles, out);
    } else {
        backproj_f32<<<NPIX / 4, 256, 0, stream>>>(image, angles, out);
    }
}

// Round 12
// 64.180 us; speedup vs baseline: 6.9127x; 1.1270x over previous
//
#include <hip/hip_runtime.h>
#include <hip/hip_fp16.h>

// Problem constants (fixed by setup_inputs): B=2, N=96, L=128
#define NANG 96
#define LDIM 128
#define NPIX (LDIM * LDIM)                 // 16384
#define IMG_ELEMS (2 * NANG * LDIM * LDIM) // 3,145,728
#define TPX 8                              // 2x4 pixel tile per block

union H8 { float4 f4; __half2 h2[4]; };

// ---- Pre-pass: f32 [b][n][row][z] -> f16 [n][row][b][z] (R4-proven) -----
// Tap row (both b) = 512 B contiguous; row byte offset = (n*128+row)*512.
__global__ __launch_bounds__(256)
void convert_transpose(const float* __restrict__ in, __half* __restrict__ out) {
    const int i = blockIdx.x * 256 + threadIdx.x;  // one thread per 8 elems
    const int rowid = i >> 4;                      // global input row (b,n,row)
    const int zo = i & 15;
    const int b = rowid / (NANG * LDIM);
    const int rem = rowid - b * (NANG * LDIM);     // n*128 + row

    const float4 a = *(const float4*)(in + (size_t)i * 8);
    const float4 c = *(const float4*)(in + (size_t)i * 8 + 4);
    H8 u;
    u.h2[0] = __float22half2_rn(make_float2(a.x, a.y));
    u.h2[1] = __float22half2_rn(make_float2(a.z, a.w));
    u.h2[2] = __float22half2_rn(make_float2(c.x, c.y));
    u.h2[3] = __float22half2_rn(make_float2(c.z, c.w));
    *(float4*)(out + ((size_t)(rem * 2 + b) * LDIM + zo * 8)) = u.f4;
}

// ---- Barrier-free direct-L1/L2 backprojection ---------------------------
// Block = 256 threads; tile = 2(r) x 4(q) = 8 pixels; 32 threads per pixel
// (b = (tid>>4)&1, zo = tid&15 -> 8 halfs per thread). No stage buffer, no
// main-loop barriers: taps read straight through L1 (block working set
// ~3.5 KB/angle), waves free-run so TCP and VALU overlap across waves.
// 8 blocks/CU = 2048 threads = full occupancy (LDS only ~7 KB).
__global__ __launch_bounds__(256)
void backproj_direct(const __half* __restrict__ imgh,   // [n][row][b][z] f16
                     const float* __restrict__ angles,  // [N]
                     float* __restrict__ out)           // [B, L, L, L] f32
{
    __shared__ float2 strig[NANG];         // 768 B  (s, c)
    __shared__ uint2  geo[TPX][NANG];      // 6144 B (wA|wB halfs, rowA|rowB)
    __shared__ float  snorm[TPX];          // 32 B

    const int tid = threadIdx.x;
    const int rt = blockIdx.x >> 5;    // 0..63
    const int qt = blockIdx.x & 31;    // 0..31
    const int r0 = rt * 2;
    const int q0 = qt * 4;

    // ---- Phase 0: per-angle sincos ----
    if (tid < NANG) {
        float s, c;
        sincosf((270.0f - angles[tid]) * 0.017453292519943295f, &s, &c);
        strig[tid] = make_float2(s, c);
    }
    if (tid < TPX) snorm[tid] = 0.0f;
    __syncthreads();

    // ---- Phase 1: geometry (8 px x 96 angles), 3 entries/thread ----
    for (int e = tid; e < TPX * NANG; e += 256) {
        const int px = e / NANG;           // 0..7
        const int n  = e - px * NANG;
        const float2 m = strig[n];
        const float s = m.x, c = m.y;

        const float xr = (float)(q0 + (px & 3)) - 63.5f;
        const float yr = (float)(r0 + (px >> 2)) - 63.5f;
        const float sx =  c * xr + s * yr + 63.5f;
        const float sy = -s * xr + c * yr + 63.5f;

        const float x0f = floorf(sx), y0f = floorf(sy);
        const float wx = sx - x0f, wy = sy - y0f;
        const int x0 = (int)x0f, y0 = (int)y0f;

        const float vy0 = (y0 >= 0 && y0 < LDIM)         ? 1.0f : 0.0f;
        const float vy1 = (y0 + 1 >= 0 && y0 + 1 < LDIM) ? 1.0f : 0.0f;
        const float vx0 = (x0 >= 0 && x0 < LDIM)         ? 1.0f : 0.0f;
        const float vx1 = (x0 + 1 >= 0 && x0 + 1 < LDIM) ? 1.0f : 0.0f;
        const float ycomb = vy0 * (1.0f - wy) + vy1 * wy;

        const float wA = (1.0f - wx) * ycomb * vx0;
        const float wB = wx * ycomb * vx1;

        const int rowA = min(max(x0, 0), LDIM - 1);        // weight 0 when OOB
        const int rowB = min(max(x0 + 1, 0), LDIM - 1);

        const ushort ha = __half_as_ushort(__float2half(wA));
        const ushort hb = __half_as_ushort(__float2half(wB));
        geo[px][e - px * NANG] = make_uint2((uint)ha | ((uint)hb << 16),
                                            (uint)rowA | ((uint)rowB << 16));
        atomicAdd(&snorm[px], wA + wB);   // norm is data-independent
    }
    __syncthreads();

    // ---- Phase 2: barrier-free accumulation over angles ----
    const int px = tid >> 5;            // 0..7
    const int b  = (tid >> 4) & 1;
    const int zo = tid & 15;
    const int laneoff = b * 256 + zo * 16;   // byte offset within 512 B row

    const char* __restrict__ base = (const char*)imgh + laneoff;
    const uint2* __restrict__ gb = &geo[px][0];

    __half2 acc[4] = {};

    #pragma unroll 4
    for (int a = 0; a < NANG; ++a) {
        const uint2 g = gb[a];
        const __half2 wa2 = __half2half2(__ushort_as_half((ushort)(g.x & 0xffff)));
        const __half2 wb2 = __half2half2(__ushort_as_half((ushort)(g.x >> 16)));
        const int addrA = ((a << 7) + (int)(g.y & 0xffff)) << 9;
        const int addrB = ((a << 7) + (int)(g.y >> 16)) << 9;
        H8 u0, u1;
        u0.f4 = *(const float4*)(base + addrA);
        u1.f4 = *(const float4*)(base + addrB);
        #pragma unroll
        for (int k = 0; k < 4; ++k) {
            acc[k] = __hfma2(wa2, u0.h2[k], acc[k]);
            acc[k] = __hfma2(wb2, u1.h2[k], acc[k]);
        }
    }

    // ---- Epilogue: fp16 acc -> f32, divide by precomputed norm ----
    const int r = r0 + (px >> 2);
    const int q = q0 + (px & 3);
    const float inv = 1.0f / (snorm[px] + 1e-11f);
    const float2 f0 = __half22float2(acc[0]);
    const float2 f1 = __half22float2(acc[1]);
    const float2 f2 = __half22float2(acc[2]);
    const float2 f3 = __half22float2(acc[3]);
    float* op = out + ((((size_t)b * LDIM + r) * LDIM + q) * LDIM + zo * 8);
    *(float4*)op     = make_float4(f0.x * inv, f0.y * inv, f1.x * inv, f1.y * inv);
    *(float4*)(op+4) = make_float4(f2.x * inv, f2.y * inv, f3.x * inv, f3.y * inv);
}

// ---- Fallback f32 kernel (proven in R0) if ws can't hold fp16 image ----
__global__ __launch_bounds__(256)
void backproj_f32(const float* __restrict__ image,
                  const float* __restrict__ angles,
                  float* __restrict__ out)
{
    __shared__ float4 geo[4 * NANG];
    const int tid = threadIdx.x;
    const int p0 = blockIdx.x * 4;

    for (int e = tid; e < 4 * NANG; e += 256) {
        const int sub = e / NANG;
        const int n   = e - sub * NANG;
        const int p   = p0 + sub;
        const int r   = p >> 7;
        const int q   = p & 127;
        float s, c;
        sincosf((270.0f - angles[n]) * 0.017453292519943295f, &s, &c);
        const float xr = (float)q - 63.5f;
        const float yr = (float)r - 63.5f;
        const float sx =  c * xr + s * yr + 63.5f;
        const float sy = -s * xr + c * yr + 63.5f;
        const float x0f = floorf(sx), y0f = floorf(sy);
        const float wx = sx - x0f, wy = sy - y0f;
        const int x0 = (int)x0f, y0 = (int)y0f;
        const float vy0 = (y0 >= 0 && y0 < LDIM) ? 1.0f : 0.0f;
        const float vy1 = (y0 + 1 >= 0 && y0 + 1 < LDIM) ? 1.0f : 0.0f;
        const float vx0 = (x0 >= 0 && x0 < LDIM) ? 1.0f : 0.0f;
        const float vx1 = (x0 + 1 >= 0 && x0 + 1 < LDIM) ? 1.0f : 0.0f;
        const float ycomb = vy0 * (1.0f - wy) + vy1 * wy;
        geo[e] = make_float4((1.0f - wx) * ycomb * vx0, wx * ycomb * vx1,
                             __int_as_float(min(max(x0, 0), LDIM - 1) * LDIM),
                             __int_as_float(min(max(x0 + 1, 0), LDIM - 1) * LDIM));
    }
    __syncthreads();

    const int sub  = tid >> 6;
    const int lane = tid & 63;
    const int b    = lane >> 5;
    const int z    = (lane & 31) * 4;
    const int p    = p0 + sub;
    const int r    = p >> 7;
    const int q    = p & 127;

    const float* imgb = image + (size_t)b * NANG * NPIX + z;
    const float4* __restrict__ gbase = &geo[sub * NANG];
    float4 acc = make_float4(0.f, 0.f, 0.f, 0.f);
    float nacc = 0.f;

    #pragma unroll 4
    for (int n = 0; n < NANG; ++n) {
        const float4 g = gbase[n];
        const float* rowbase = imgb + n * NPIX;
        const float4 v0 = *(const float4*)(rowbase + __float_as_int(g.z));
        const float4 v1 = *(const float4*)(rowbase + __float_as_int(g.w));
        acc.x = fmaf(g.x, v0.x, fmaf(g.y, v1.x, acc.x));
        acc.y = fmaf(g.x, v0.y, fmaf(g.y, v1.y, acc.y));
        acc.z = fmaf(g.x, v0.z, fmaf(g.y, v1.z, acc.z));
        acc.w = fmaf(g.x, v0.w, fmaf(g.y, v1.w, acc.w));
        nacc += g.x + g.y;
    }
    const float inv = 1.0f / (nacc + 1e-11f);
    *(float4*)(out + ((((size_t)b * LDIM + r) * LDIM + q) * LDIM + z)) =
        make_float4(acc.x * inv, acc.y * inv, acc.z * inv, acc.w * inv);
}

extern "C" void kernel_launch(void* const* d_in, const int* in_sizes, int n_in,
                              void* d_out, int out_size, void* d_ws, size_t ws_size,
                              hipStream_t stream) {
    const float* image  = (const float*)d_in[0];   // [2, 96, 128, 128] f32
    const float* angles = (const float*)d_in[1];   // [96] f32
    float* out = (float*)d_out;                    // [2, 128, 128, 128] f32

    const size_t need = (size_t)IMG_ELEMS * sizeof(__half);  // 6.29 MB
    if (ws_size >= need) {
        __half* imgh = (__half*)d_ws;
        convert_transpose<<<IMG_ELEMS / 8 / 256, 256, 0, stream>>>(image, imgh);
        backproj_direct<<<2048, 256, 0, stream>>>(imgh, angles, out);
    } else {
        backproj_f32<<<NPIX / 4, 256, 0, stream>>>(image, angles, out);
    }
}